// Round 4
// baseline (391.692 us; speedup 1.0000x reference)
//
#include <hip/hip_runtime.h>
#include <math.h>

#define BB 16
#define NN 4096
#define MM 1024
#define KNN 32
#define R2 0.04f
#define EPSV 1e-5f
#define S1f ((float)(BB * MM * KNN))
#define S3f ((float)(BB * MM))

typedef __attribute__((ext_vector_type(8))) short short8;
typedef __attribute__((ext_vector_type(4))) short short4v;
typedef __attribute__((ext_vector_type(4))) float f32x4;

__device__ __forceinline__ short f2b(float x) {
    union { float f; unsigned u; } v; v.f = x;
    unsigned r = v.u + 0x7fffu + ((v.u >> 16) & 1u);
    return (short)(r >> 16);
}
__device__ __forceinline__ float gelu_t(float x) {  // tanh-approx (inner layers)
    float u = 0.7978845608f * x * (1.f + 0.044715f * x * x);
    float t = 1.f - 2.f / (__expf(2.f * u) + 1.f);
    return 0.5f * x * (1.f + t);
}
__device__ __forceinline__ float gelu_e(float x) {  // exact (final output)
    return 0.5f * x * (1.f + erff(x * 0.7071067811865475f));
}
__device__ __forceinline__ f32x4 zero4() { f32x4 z = {0.f, 0.f, 0.f, 0.f}; return z; }
__device__ __forceinline__ f32x4 mfma(short8 a, short8 b, f32x4 c) {
    return __builtin_amdgcn_mfma_f32_16x16x32_bf16(a, b, c, 0, 0, 0);
}
__device__ __forceinline__ short8 pack8(f32x4 a, f32x4 b) {
    short8 r;
    r[0] = f2b(a[0]); r[1] = f2b(a[1]); r[2] = f2b(a[2]); r[3] = f2b(a[3]);
    r[4] = f2b(b[0]); r[5] = f2b(b[1]); r[6] = f2b(b[2]); r[7] = f2b(b[3]);
    return r;
}
__device__ __forceinline__ float red16(float v) {
    v += __shfl_xor(v, 1); v += __shfl_xor(v, 2);
    v += __shfl_xor(v, 4); v += __shfl_xor(v, 8);
    return v;
}

// ---------------- ball query: one query per wave ----------------
__global__ __launch_bounds__(256) void k_ballquery(const float* __restrict__ src_xyz,
                                                   const float* __restrict__ xyz,
                                                   int* __restrict__ gidx) {
    __shared__ float sx[NN], sy[NN], sz[NN];
    int t = threadIdx.x;
    int lane = t & 63, w = t >> 6;
    int q0 = blockIdx.x * 16;
    int b = q0 >> 10;
    const float* sp = src_xyz + (size_t)b * NN * 3;
    for (int i = t; i < NN * 3; i += 256) {
        float v = sp[i];
        int j = i / 3, d = i - j * 3;
        if (d == 0) sx[j] = v;
        else if (d == 1) sy[j] = v;
        else sz[j] = v;
    }
    __syncthreads();
#pragma unroll
    for (int qi = 0; qi < 4; ++qi) {
        int q = q0 + w * 4 + qi;
        int m = q & 1023;
        float qx = xyz[((size_t)b * MM + m) * 3 + 0];
        float qy = xyz[((size_t)b * MM + m) * 3 + 1];
        float qz = xyz[((size_t)b * MM + m) * 3 + 2];
        int* outp = gidx + (size_t)q * KNN;
        int cnt = 0, firstj = -1;
        for (int j0 = 0; j0 < NN && cnt < KNN; j0 += 64) {
            int j = j0 + lane;
            float dx = qx - sx[j];
            float dy = qy - sy[j];
            float dz = qz - sz[j];
            bool hit = (dx * dx + dy * dy + dz * dz) <= R2;
            unsigned long long mask = __ballot(hit);
            if (hit) {
                int rank = cnt + __popcll(mask & ((1ull << lane) - 1ull));
                if (rank < KNN) outp[rank] = j;
            }
            if (firstj < 0 && mask != 0ull) firstj = j0 + __ffsll((long long)mask) - 1;
            cnt += __popcll(mask);
        }
        if (cnt < KNN) {
            int fj = (firstj < 0) ? 0 : firstj;
            for (int k = cnt + lane; k < KNN; k += 64) outp[k] = fj;
        }
    }
}

// ---------------- weights -> bf16 ----------------
// w1 reordered: col 0..63 = orig cols 3..66 (src_x), 64..66 = orig 0..2 (xyz), 67..95 = 0
__global__ __launch_bounds__(256) void k_prep(const float* __restrict__ w1,
                                              const float* __restrict__ w2,
                                              const float* __restrict__ w3,
                                              short* __restrict__ w1b,
                                              short* __restrict__ w2b,
                                              short* __restrict__ w3b) {
    int i = blockIdx.x * 256 + threadIdx.x;
    if (i < 64 * 96) {
        int n = i / 96, k = i % 96;
        float v = 0.f;
        if (k < 64) v = w1[n * 67 + 3 + k];
        else if (k < 67) v = w1[n * 67 + (k - 64)];
        w1b[i] = f2b(v);
    } else if (i < 64 * 96 + 128 * 64) {
        int j = i - 64 * 96;
        w2b[j] = f2b(w2[j]);
    } else if (i < 64 * 96 + 128 * 64 + 256 * 128) {
        int j = i - (64 * 96 + 128 * 64);
        w3b[j] = f2b(w3[j]);
    }
}

// ---------------- per-lane feat fragment gather (no LDS, no barrier) ----------------
// B-frag for a 16-row tile at tileRow0: lane holds feat[row=tileRow0+(lane&15)][k-chunk].
__device__ __forceinline__ void gather_frags(const int* __restrict__ gidx,
                                             const float* __restrict__ src_x,
                                             const float* __restrict__ src_xyz,
                                             float qx, float qy, float qz,
                                             int b, int tileRow0, int lane,
                                             short8& f0, short8& f1, short8& f2) {
    int r = tileRow0 + (lane & 15);
    int j = gidx[(size_t)(r >> 5) * KNN + (r & 31)];
    int qq = lane >> 4;
    const float* xp = src_x + ((size_t)b * NN + j) * 64 + qq * 8;
    f32x4 v0 = *(const f32x4*)xp;
    f32x4 v1 = *(const f32x4*)(xp + 4);
    f0 = pack8(v0, v1);
    f32x4 v2 = *(const f32x4*)(xp + 32);
    f32x4 v3 = *(const f32x4*)(xp + 36);
    f1 = pack8(v2, v3);
    short8 z = {0, 0, 0, 0, 0, 0, 0, 0};
    if (qq == 0) {
        const float* spp = src_xyz + ((size_t)b * NN + j) * 3;
        z[0] = f2b(spp[0] - qx); z[1] = f2b(spp[1] - qy); z[2] = f2b(spp[2] - qz);
    }
    f2 = z;
}

// ---------------- layer1: D1[o1][sample] = mfma(W1, feat) for wave's 32 rows ----------------
__device__ __forceinline__ void layer1(const int* __restrict__ gidx,
                                       const float* __restrict__ src_x,
                                       const float* __restrict__ src_xyz,
                                       const short* __restrict__ w1b,
                                       int b, int waveRow0,
                                       float qx, float qy, float qz,
                                       int lane, f32x4 acc[2][4]) {
#pragma unroll
    for (int rf = 0; rf < 2; ++rf)
#pragma unroll
        for (int nf = 0; nf < 4; ++nf) acc[rf][nf] = zero4();
    int qq = lane >> 4;
#pragma unroll
    for (int rf = 0; rf < 2; ++rf) {
        short8 f0, f1, f2;
        gather_frags(gidx, src_x, src_xyz, qx, qy, qz, b, waveRow0 + rf * 16, lane, f0, f1, f2);
#pragma unroll
        for (int kf = 0; kf < 3; ++kf) {
            short8 fb = (kf == 0) ? f0 : (kf == 1) ? f1 : f2;
#pragma unroll
            for (int nf = 0; nf < 4; ++nf) {
                short8 aW = *(const short8*)(w1b + (nf * 16 + (lane & 15)) * 96 + kf * 32 + qq * 8);
                acc[rf][nf] = mfma(aW, fb, acc[rf][nf]);
            }
        }
    }
}

// ---------------- stats1: column stats of pre-h1 ----------------
__global__ __launch_bounds__(256, 4) void k_s1(const int* __restrict__ gidx,
                                               const float* __restrict__ src_xyz,
                                               const float* __restrict__ xyz,
                                               const float* __restrict__ src_x,
                                               const short* __restrict__ w1b,
                                               float* __restrict__ stats1) {
    __shared__ float redS[256], redQ[256];
    int t = threadIdx.x, lane = t & 63, w = t >> 6;
    int gg = blockIdx.x * 4 + w;
    int b = gg >> 10, m = gg & 1023;
    float qx = xyz[((size_t)b * MM + m) * 3 + 0];
    float qy = xyz[((size_t)b * MM + m) * 3 + 1];
    float qz = xyz[((size_t)b * MM + m) * 3 + 2];
    f32x4 acc[2][4];
    layer1(gidx, src_x, src_xyz, w1b, b, gg * 32, qx, qy, qz, lane, acc);
#pragma unroll
    for (int nf = 0; nf < 4; ++nf)
#pragma unroll
        for (int j = 0; j < 4; ++j) {
            float a0 = acc[0][nf][j], a1 = acc[1][nf][j];
            float s = red16(a0 + a1);
            float sq = red16(a0 * a0 + a1 * a1);
            if ((lane & 15) == 0) {
                redS[w * 64 + nf * 16 + (lane >> 4) * 4 + j] = s;
                redQ[w * 64 + nf * 16 + (lane >> 4) * 4 + j] = sq;
            }
        }
    __syncthreads();
    if (t < 64) {
        float s = redS[t] + redS[64 + t] + redS[128 + t] + redS[192 + t];
        float sq = redQ[t] + redQ[64 + t] + redQ[128 + t] + redQ[192 + t];
        float* st = stats1 + (blockIdx.x & 7) * 128;
        atomicAdd(&st[t], s);
        atomicAdd(&st[64 + t], sq);
    }
}

// ---------------- stats2: recompute h1, column stats of pre-h2 ----------------
__global__ __launch_bounds__(256, 4) void k_s2(const int* __restrict__ gidx,
                                               const float* __restrict__ src_xyz,
                                               const float* __restrict__ xyz,
                                               const float* __restrict__ src_x,
                                               const short* __restrict__ w1b,
                                               const short* __restrict__ w2b,
                                               const float* __restrict__ g1,
                                               const float* __restrict__ b1,
                                               const float* __restrict__ stats1,
                                               float* __restrict__ stats2) {
    __shared__ short h1S[128 * 72];
    __shared__ float sc1L[64], sh1L[64];
    __shared__ float redS[512], redQ[512];
    int t = threadIdx.x, lane = t & 63, w = t >> 6;
    if (t < 64) {
        float s = 0.f, sq = 0.f;
#pragma unroll
        for (int r = 0; r < 8; ++r) { s += stats1[r * 128 + t]; sq += stats1[r * 128 + 64 + t]; }
        float mu = s * (1.f / S1f);
        float var = sq * (1.f / S1f) - mu * mu;
        float rs = rsqrtf(var + EPSV);
        float sc = g1[t] * rs;
        sc1L[t] = sc;
        sh1L[t] = b1[t] - mu * sc;
    }
    __syncthreads();
    int gg = blockIdx.x * 4 + w;
    int b = gg >> 10, m = gg & 1023;
    float qx = xyz[((size_t)b * MM + m) * 3 + 0];
    float qy = xyz[((size_t)b * MM + m) * 3 + 1];
    float qz = xyz[((size_t)b * MM + m) * 3 + 2];
    f32x4 acc[2][4];
    layer1(gidx, src_x, src_xyz, w1b, b, gg * 32, qx, qy, qz, lane, acc);
    int qq = lane >> 4;
    // epilogue: BN1+gelu -> h1S (own rows, packed b64)
#pragma unroll
    for (int rf = 0; rf < 2; ++rf)
#pragma unroll
        for (int nf = 0; nf < 4; ++nf) {
            int row = w * 32 + rf * 16 + (lane & 15);
            int o0 = nf * 16 + qq * 4;
            short4v sv;
#pragma unroll
            for (int j = 0; j < 4; ++j)
                sv[j] = f2b(gelu_t(acc[rf][nf][j] * sc1L[o0 + j] + sh1L[o0 + j]));
            *(short4v*)(h1S + row * 72 + o0) = sv;
        }
    // L2: D2[o2][sample]
    f32x4 acc2[2][8];
#pragma unroll
    for (int rf = 0; rf < 2; ++rf)
#pragma unroll
        for (int nf = 0; nf < 8; ++nf) acc2[rf][nf] = zero4();
#pragma unroll
    for (int rf = 0; rf < 2; ++rf) {
        short8 hB[2];
#pragma unroll
        for (int kf = 0; kf < 2; ++kf)
            hB[kf] = *(const short8*)(h1S + (w * 32 + rf * 16 + (lane & 15)) * 72 + kf * 32 + qq * 8);
#pragma unroll
        for (int kf = 0; kf < 2; ++kf)
#pragma unroll
            for (int nf = 0; nf < 8; ++nf) {
                short8 aW = *(const short8*)(w2b + (nf * 16 + (lane & 15)) * 64 + kf * 32 + qq * 8);
                acc2[rf][nf] = mfma(aW, hB[kf], acc2[rf][nf]);
            }
    }
#pragma unroll
    for (int nf = 0; nf < 8; ++nf)
#pragma unroll
        for (int j = 0; j < 4; ++j) {
            float a0 = acc2[0][nf][j], a1 = acc2[1][nf][j];
            float s = red16(a0 + a1);
            float sq = red16(a0 * a0 + a1 * a1);
            if ((lane & 15) == 0) {
                redS[w * 128 + nf * 16 + qq * 4 + j] = s;
                redQ[w * 128 + nf * 16 + qq * 4 + j] = sq;
            }
        }
    __syncthreads();
    if (t < 128) {
        float s = redS[t] + redS[128 + t] + redS[256 + t] + redS[384 + t];
        float sq = redQ[t] + redQ[128 + t] + redQ[256 + t] + redQ[384 + t];
        float* st = stats2 + (blockIdx.x & 7) * 256;
        atomicAdd(&st[t], s);
        atomicAdd(&st[128 + t], sq);
    }
}

// ---------------- layer3: recompute h1,h2 (barrier-free), einsum3 + max ----------------
__global__ __launch_bounds__(256, 3) void k_l3(const int* __restrict__ gidx,
                                               const float* __restrict__ src_xyz,
                                               const float* __restrict__ xyz,
                                               const float* __restrict__ src_x,
                                               const short* __restrict__ w1b,
                                               const short* __restrict__ w2b,
                                               const short* __restrict__ w3b,
                                               const float* __restrict__ g1,
                                               const float* __restrict__ b1,
                                               const float* __restrict__ g2,
                                               const float* __restrict__ b2,
                                               const float* __restrict__ stats1,
                                               const float* __restrict__ stats2,
                                               float* __restrict__ out) {
    __shared__ short h1S[128 * 72];    // stride 72 (144B: 16B-mult, 2-way banks)
    __shared__ short h2S[128 * 132];   // stride 132 (264B: 8B-mult, b64 reads)
    __shared__ float sc1L[64], sh1L[64], sc2L[128], sh2L[128];
    int t = threadIdx.x, lane = t & 63, w = t >> 6;
    if (t < 64) {
        float s = 0.f, sq = 0.f;
#pragma unroll
        for (int r = 0; r < 8; ++r) { s += stats1[r * 128 + t]; sq += stats1[r * 128 + 64 + t]; }
        float mu = s * (1.f / S1f);
        float var = sq * (1.f / S1f) - mu * mu;
        float rs = rsqrtf(var + EPSV);
        float sc = g1[t] * rs;
        sc1L[t] = sc;
        sh1L[t] = b1[t] - mu * sc;
    }
    if (t < 128) {
        float s = 0.f, sq = 0.f;
#pragma unroll
        for (int r = 0; r < 8; ++r) { s += stats2[r * 256 + t]; sq += stats2[r * 256 + 128 + t]; }
        float mu = s * (1.f / S1f);
        float var = sq * (1.f / S1f) - mu * mu;
        float rs = rsqrtf(var + EPSV);
        float sc = g2[t] * rs;
        sc2L[t] = sc;
        sh2L[t] = b2[t] - mu * sc;
    }
    __syncthreads();  // the only barrier
    int gg = blockIdx.x * 4 + w;
    int b = gg >> 10, m = gg & 1023;
    float qx = xyz[((size_t)b * MM + m) * 3 + 0];
    float qy = xyz[((size_t)b * MM + m) * 3 + 1];
    float qz = xyz[((size_t)b * MM + m) * 3 + 2];
    f32x4 acc[2][4];
    layer1(gidx, src_x, src_xyz, w1b, b, gg * 32, qx, qy, qz, lane, acc);
    int qq = lane >> 4;
#pragma unroll
    for (int rf = 0; rf < 2; ++rf)
#pragma unroll
        for (int nf = 0; nf < 4; ++nf) {
            int row = w * 32 + rf * 16 + (lane & 15);
            int o0 = nf * 16 + qq * 4;
            short4v sv;
#pragma unroll
            for (int j = 0; j < 4; ++j)
                sv[j] = f2b(gelu_t(acc[rf][nf][j] * sc1L[o0 + j] + sh1L[o0 + j]));
            *(short4v*)(h1S + row * 72 + o0) = sv;
        }
    // L2
    f32x4 acc2[2][8];
#pragma unroll
    for (int rf = 0; rf < 2; ++rf)
#pragma unroll
        for (int nf = 0; nf < 8; ++nf) acc2[rf][nf] = zero4();
#pragma unroll
    for (int rf = 0; rf < 2; ++rf) {
        short8 hB[2];
#pragma unroll
        for (int kf = 0; kf < 2; ++kf)
            hB[kf] = *(const short8*)(h1S + (w * 32 + rf * 16 + (lane & 15)) * 72 + kf * 32 + qq * 8);
#pragma unroll
        for (int kf = 0; kf < 2; ++kf)
#pragma unroll
            for (int nf = 0; nf < 8; ++nf) {
                short8 aW = *(const short8*)(w2b + (nf * 16 + (lane & 15)) * 64 + kf * 32 + qq * 8);
                acc2[rf][nf] = mfma(aW, hB[kf], acc2[rf][nf]);
            }
    }
#pragma unroll
    for (int rf = 0; rf < 2; ++rf)
#pragma unroll
        for (int nf = 0; nf < 8; ++nf) {
            int row = w * 32 + rf * 16 + (lane & 15);
            int o0 = nf * 16 + qq * 4;
            short4v sv;
#pragma unroll
            for (int j = 0; j < 4; ++j)
                sv[j] = f2b(gelu_t(acc2[rf][nf][j] * sc2L[o0 + j] + sh2L[o0 + j]));
            *(short4v*)(h2S + row * 132 + o0) = sv;
        }
    // L3: 4 chunks of 64 output channels, w3 frags from global (L2-resident)
#pragma unroll
    for (int nc = 0; nc < 4; ++nc) {
        f32x4 acc3[2][4];
#pragma unroll
        for (int rf = 0; rf < 2; ++rf)
#pragma unroll
            for (int nf = 0; nf < 4; ++nf) acc3[rf][nf] = zero4();
#pragma unroll
        for (int rf = 0; rf < 2; ++rf) {
            short8 h2f[4];
#pragma unroll
            for (int kf = 0; kf < 4; ++kf) {
                const short* p = h2S + (w * 32 + rf * 16 + (lane & 15)) * 132 + kf * 32 + qq * 8;
                short4v lo = *(const short4v*)p;
                short4v hi = *(const short4v*)(p + 4);
                h2f[kf] = __builtin_shufflevector(lo, hi, 0, 1, 2, 3, 4, 5, 6, 7);
            }
#pragma unroll
            for (int kf = 0; kf < 4; ++kf)
#pragma unroll
                for (int nf = 0; nf < 4; ++nf) {
                    short8 aW = *(const short8*)(w3b + (size_t)(nc * 64 + nf * 16 + (lane & 15)) * 128 + kf * 32 + qq * 8);
                    acc3[rf][nf] = mfma(aW, h2f[kf], acc3[rf][nf]);
                }
        }
#pragma unroll
        for (int nf = 0; nf < 4; ++nf) {
            float mv[4];
#pragma unroll
            for (int j = 0; j < 4; ++j) {
                float v = fmaxf(acc3[0][nf][j], acc3[1][nf][j]);
                v = fmaxf(v, __shfl_xor(v, 1));
                v = fmaxf(v, __shfl_xor(v, 2));
                v = fmaxf(v, __shfl_xor(v, 4));
                v = fmaxf(v, __shfl_xor(v, 8));
                mv[j] = v;
            }
            if ((lane & 15) == 0) {
                f32x4 st = {mv[0], mv[1], mv[2], mv[3]};
                *(f32x4*)(out + (size_t)gg * 256 + nc * 64 + nf * 16 + qq * 4) = st;
            }
        }
    }
}

// ---------------- stats3 + final BN/GELU ----------------
__global__ __launch_bounds__(256) void k_stats3(const float* __restrict__ out,
                                                float* __restrict__ stats3) {
    int t = threadIdx.x;
    float s = 0.f, q = 0.f;
    const float* p = out + (size_t)blockIdx.x * 128 * 256 + t;
    for (int r = 0; r < 128; ++r) { float v = p[r * 256]; s += v; q += v * v; }
    atomicAdd(&stats3[t], s);
    atomicAdd(&stats3[256 + t], q);
}

__global__ __launch_bounds__(256) void k_bn3(float* __restrict__ out,
                                             const float* __restrict__ stats3,
                                             const float* __restrict__ gl,
                                             const float* __restrict__ bl) {
    int i = blockIdx.x * 256 + threadIdx.x;
    int o = i & 255;
    float mu = stats3[o] * (1.f / S3f);
    float var = stats3[256 + o] * (1.f / S3f) - mu * mu;
    float rs = rsqrtf(var + EPSV);
    float x = out[i];
    out[i] = gelu_e((x - mu) * rs * gl[o] + bl[o]);
}

extern "C" void kernel_launch(void* const* d_in, const int* in_sizes, int n_in,
                              void* d_out, int out_size, void* d_ws, size_t ws_size,
                              hipStream_t stream) {
    const float* src_x   = (const float*)d_in[0];
    const float* src_xyz = (const float*)d_in[1];
    const float* xyz     = (const float*)d_in[2];
    const float* w1      = (const float*)d_in[3];
    const float* g1      = (const float*)d_in[4];
    const float* b1      = (const float*)d_in[5];
    const float* w2      = (const float*)d_in[6];
    const float* g2      = (const float*)d_in[7];
    const float* b2      = (const float*)d_in[8];
    const float* w3      = (const float*)d_in[9];
    const float* gl      = (const float*)d_in[10];
    const float* bl      = (const float*)d_in[11];
    float* out = (float*)d_out;

    int* gidx = (int*)d_ws;
    float* statsF = (float*)(gidx + BB * MM * KNN);
    float* stats1 = statsF;          // 8 slots x (64 sum | 64 sq)
    float* stats2 = statsF + 1024;   // 8 slots x (128 sum | 128 sq)
    float* stats3 = statsF + 3072;   // 256 sum + 256 sq
    short* wb = (short*)(statsF + 3584);
    short* w1b = wb;                 // [64][96] reordered
    short* w2b = wb + 6144;          // [128][64]
    short* w3b = wb + 14336;         // [256][128]

    hipMemsetAsync(statsF, 0, 3584 * sizeof(float), stream);
    k_prep<<<184, 256, 0, stream>>>(w1, w2, w3, w1b, w2b, w3b);
    k_ballquery<<<(BB * MM) / 16, 256, 0, stream>>>(src_xyz, xyz, gidx);
    k_s1<<<(BB * MM) / 4, 256, 0, stream>>>(gidx, src_xyz, xyz, src_x, w1b, stats1);
    k_s2<<<(BB * MM) / 4, 256, 0, stream>>>(gidx, src_xyz, xyz, src_x, w1b, w2b, g1, b1,
                                            stats1, stats2);
    k_l3<<<(BB * MM) / 4, 256, 0, stream>>>(gidx, src_xyz, xyz, src_x, w1b, w2b, w3b,
                                            g1, b1, g2, b2, stats1, stats2, out);
    k_stats3<<<(BB * MM) / 128, 256, 0, stream>>>(out, stats3);
    k_bn3<<<BB * MM, 256, 0, stream>>>(out, stats3, gl, bl);
}

// Round 5
// 360.572 us; speedup vs baseline: 1.0863x; 1.0863x over previous
//
#include <hip/hip_runtime.h>
#include <math.h>

#define BB 16
#define NN 4096
#define MM 1024
#define KNN 32
#define R2 0.04f
#define EPSV 1e-5f
#define S1f ((float)(BB * MM * KNN))
#define S3f ((float)(BB * MM))

typedef __attribute__((ext_vector_type(8))) short short8;
typedef __attribute__((ext_vector_type(4))) short short4v;
typedef __attribute__((ext_vector_type(4))) float f32x4;

__device__ __forceinline__ short f2b(float x) {
    union { float f; unsigned u; } v; v.f = x;
    unsigned r = v.u + 0x7fffu + ((v.u >> 16) & 1u);
    return (short)(r >> 16);
}
__device__ __forceinline__ float gelu_t(float x) {  // tanh-approx (inner layers)
    float u = 0.7978845608f * x * (1.f + 0.044715f * x * x);
    float t = 1.f - 2.f / (__expf(2.f * u) + 1.f);
    return 0.5f * x * (1.f + t);
}
__device__ __forceinline__ float gelu_e(float x) {  // exact (final output)
    return 0.5f * x * (1.f + erff(x * 0.7071067811865475f));
}
__device__ __forceinline__ f32x4 zero4() { f32x4 z = {0.f, 0.f, 0.f, 0.f}; return z; }
__device__ __forceinline__ f32x4 mfma(short8 a, short8 b, f32x4 c) {
    return __builtin_amdgcn_mfma_f32_16x16x32_bf16(a, b, c, 0, 0, 0);
}
__device__ __forceinline__ short8 pack8(f32x4 a, f32x4 b) {
    short8 r;
    r[0] = f2b(a[0]); r[1] = f2b(a[1]); r[2] = f2b(a[2]); r[3] = f2b(a[3]);
    r[4] = f2b(b[0]); r[5] = f2b(b[1]); r[6] = f2b(b[2]); r[7] = f2b(b[3]);
    return r;
}
__device__ __forceinline__ short8 ld8(const short* p) {  // LDS 8B-aligned pair load
    short4v a = *(const short4v*)p;
    short4v b = *(const short4v*)(p + 4);
    return __builtin_shufflevector(a, b, 0, 1, 2, 3, 4, 5, 6, 7);
}

// ---------------- ball query: one query per wave ----------------
__global__ __launch_bounds__(256) void k_ballquery(const float* __restrict__ src_xyz,
                                                   const float* __restrict__ xyz,
                                                   int* __restrict__ gidx) {
    __shared__ float sx[NN], sy[NN], sz[NN];
    int t = threadIdx.x;
    int lane = t & 63, w = t >> 6;
    int q0 = blockIdx.x * 16;
    int b = q0 >> 10;
    const float* sp = src_xyz + (size_t)b * NN * 3;
    for (int i = t; i < NN * 3; i += 256) {
        float v = sp[i];
        int j = i / 3, d = i - j * 3;
        if (d == 0) sx[j] = v;
        else if (d == 1) sy[j] = v;
        else sz[j] = v;
    }
    __syncthreads();
#pragma unroll
    for (int qi = 0; qi < 4; ++qi) {
        int q = q0 + w * 4 + qi;
        int m = q & 1023;
        float qx = xyz[((size_t)b * MM + m) * 3 + 0];
        float qy = xyz[((size_t)b * MM + m) * 3 + 1];
        float qz = xyz[((size_t)b * MM + m) * 3 + 2];
        int* outp = gidx + (size_t)q * KNN;
        int cnt = 0, firstj = -1;
        for (int j0 = 0; j0 < NN && cnt < KNN; j0 += 64) {
            int j = j0 + lane;
            float dx = qx - sx[j];
            float dy = qy - sy[j];
            float dz = qz - sz[j];
            bool hit = (dx * dx + dy * dy + dz * dz) <= R2;
            unsigned long long mask = __ballot(hit);
            if (hit) {
                int rank = cnt + __popcll(mask & ((1ull << lane) - 1ull));
                if (rank < KNN) outp[rank] = j;
            }
            if (firstj < 0 && mask != 0ull) firstj = j0 + __ffsll((long long)mask) - 1;
            cnt += __popcll(mask);
        }
        if (cnt < KNN) {
            int fj = (firstj < 0) ? 0 : firstj;
            for (int k = cnt + lane; k < KNN; k += 64) outp[k] = fj;
        }
    }
}

// ---------------- prep: src_x -> bf16; weights -> bf16 (w1 col-reordered, K-padded) ----------------
// w1b cols: 0..63 = orig 3..66 (src_x part), 64..66 = orig 0..2 (xyz), 67..95 = 0
__global__ __launch_bounds__(256) void k_prep(const float* __restrict__ src_x,
                                              const float* __restrict__ w1,
                                              const float* __restrict__ w2,
                                              const float* __restrict__ w3,
                                              short* __restrict__ src_xb,
                                              short* __restrict__ w1b,
                                              short* __restrict__ w2b,
                                              short* __restrict__ w3b) {
    int i = blockIdx.x * 256 + threadIdx.x;
    if (i < 524288) {  // BB*NN*64/8
        const f32x4* p = (const f32x4*)(src_x + (size_t)i * 8);
        *(short8*)(src_xb + (size_t)i * 8) = pack8(p[0], p[1]);
    } else {
        int j = i - 524288;
        if (j < 6144) {
            int n = j / 96, k = j % 96;
            float v = 0.f;
            if (k < 64) v = w1[n * 67 + 3 + k];
            else if (k < 67) v = w1[n * 67 + (k - 64)];
            w1b[j] = f2b(v);
        } else if (j < 14336) {
            w2b[j - 6144] = f2b(w2[j - 6144]);
        } else if (j < 47104) {
            w3b[j - 14336] = f2b(w3[j - 14336]);
        }
    }
}

// ---------------- layer1 MFMA: acc[rf][nf], D rows=samples cols=o1 ----------------
__device__ __forceinline__ void layer1(const short* featS, const short* __restrict__ w1b,
                                       int ln, int qq, int w, f32x4 acc[2][4]) {
#pragma unroll
    for (int rf = 0; rf < 2; ++rf)
#pragma unroll
        for (int nf = 0; nf < 4; ++nf) acc[rf][nf] = zero4();
#pragma unroll
    for (int kf = 0; kf < 3; ++kf) {
        short8 a0 = ld8(featS + (w * 32 + ln) * 68 + kf * 32 + qq * 8);
        short8 a1 = ld8(featS + (w * 32 + 16 + ln) * 68 + kf * 32 + qq * 8);
#pragma unroll
        for (int nf = 0; nf < 4; ++nf) {
            short8 bw = *(const short8*)(w1b + (nf * 16 + ln) * 96 + kf * 32 + qq * 8);
            acc[0][nf] = mfma(a0, bw, acc[0][nf]);
            acc[1][nf] = mfma(a1, bw, acc[1][nf]);
        }
    }
}

// gather macro body: thread t fills feat row t>>1 (wave-aligned: no post-barrier needed)
#define GATHER_FEAT(featS)                                                              \
    {                                                                                   \
        int r = t >> 1, hf = t & 1;                                                     \
        int j = sidx[r];                                                                \
        const short8* sp = (const short8*)(src_xb + ((size_t)b * NN + j) * 64 + hf * 32); \
        short* d = (featS) + r * 68 + hf * 32;                                          \
        _Pragma("unroll")                                                               \
        for (int i = 0; i < 4; ++i) {                                                   \
            short8 v = sp[i];                                                           \
            *(short4v*)(d + i * 8) = __builtin_shufflevector(v, v, 0, 1, 2, 3);         \
            *(short4v*)(d + i * 8 + 4) = __builtin_shufflevector(v, v, 4, 5, 6, 7);     \
        }                                                                               \
        if (hf == 0) {                                                                  \
            int gg = g0 + (r >> 5), m = gg & 1023;                                      \
            const float* spp = src_xyz + ((size_t)b * NN + j) * 3;                      \
            const float* qp = xyz + ((size_t)b * MM + m) * 3;                           \
            short4v z;                                                                  \
            z[0] = f2b(spp[0] - qp[0]); z[1] = f2b(spp[1] - qp[1]);                     \
            z[2] = f2b(spp[2] - qp[2]); z[3] = 0;                                       \
            *(short4v*)((featS) + r * 68 + 64) = z;                                     \
        }                                                                               \
    }

// ---------------- stats1: column stats of pre-h1 ----------------
__global__ __launch_bounds__(256, 4) void k_s1(const int* __restrict__ gidx,
                                               const float* __restrict__ src_xyz,
                                               const float* __restrict__ xyz,
                                               const short* __restrict__ src_xb,
                                               const short* __restrict__ w1b,
                                               float* __restrict__ stats1) {
    __shared__ short featS[128 * 68 + 64];
    __shared__ int sidx[128];
    __shared__ float redS[256], redQ[256];
    int t = threadIdx.x, lane = t & 63, w = t >> 6, ln = lane & 15, qq = lane >> 4;
    int g0 = blockIdx.x * 4, b = g0 >> 10;
    if (t < 128) sidx[t] = gidx[(size_t)(g0 + (t >> 5)) * KNN + (t & 31)];
    if (t < 16) { short4v z = {0, 0, 0, 0}; *(short4v*)(featS + 128 * 68 + t * 4) = z; }
    __syncthreads();
    GATHER_FEAT(featS)
    f32x4 acc[2][4];
    layer1(featS, w1b, ln, qq, w, acc);
#pragma unroll
    for (int nf = 0; nf < 4; ++nf) {
        float s = 0.f, q = 0.f;
#pragma unroll
        for (int rf = 0; rf < 2; ++rf)
#pragma unroll
            for (int j = 0; j < 4; ++j) { float v = acc[rf][nf][j]; s += v; q += v * v; }
        s += __shfl_xor(s, 16); s += __shfl_xor(s, 32);
        q += __shfl_xor(q, 16); q += __shfl_xor(q, 32);
        if (lane < 16) { redS[w * 64 + nf * 16 + lane] = s; redQ[w * 64 + nf * 16 + lane] = q; }
    }
    __syncthreads();
    if (t < 64) {
        float s = redS[t] + redS[64 + t] + redS[128 + t] + redS[192 + t];
        float q = redQ[t] + redQ[64 + t] + redQ[128 + t] + redQ[192 + t];
        float* st = stats1 + (blockIdx.x & 7) * 128;
        atomicAdd(&st[t], s);
        atomicAdd(&st[64 + t], q);
    }
}

// ---------------- stats2: recompute h1 (BN1+gelu), column stats of pre-h2 ----------------
__global__ __launch_bounds__(256, 3) void k_s2(const int* __restrict__ gidx,
                                               const float* __restrict__ src_xyz,
                                               const float* __restrict__ xyz,
                                               const short* __restrict__ src_xb,
                                               const short* __restrict__ w1b,
                                               const short* __restrict__ w2b,
                                               const float* __restrict__ g1,
                                               const float* __restrict__ b1,
                                               const float* __restrict__ stats1,
                                               float* __restrict__ stats2) {
    __shared__ short featS[128 * 68 + 64];
    __shared__ short h1S[128 * 68];
    __shared__ int sidx[128];
    __shared__ float sc1L[64], sh1L[64];
    __shared__ float redS[512], redQ[512];
    int t = threadIdx.x, lane = t & 63, w = t >> 6, ln = lane & 15, qq = lane >> 4;
    int g0 = blockIdx.x * 4, b = g0 >> 10;
    if (t < 128) sidx[t] = gidx[(size_t)(g0 + (t >> 5)) * KNN + (t & 31)];
    if (t < 16) { short4v z = {0, 0, 0, 0}; *(short4v*)(featS + 128 * 68 + t * 4) = z; }
    if (t < 64) {
        float s = 0.f, sq = 0.f;
#pragma unroll
        for (int r = 0; r < 8; ++r) { s += stats1[r * 128 + t]; sq += stats1[r * 128 + 64 + t]; }
        float mu = s * (1.f / S1f);
        float var = sq * (1.f / S1f) - mu * mu;
        float rs = rsqrtf(var + EPSV);
        float sc = g1[t] * rs;
        sc1L[t] = sc;
        sh1L[t] = b1[t] - mu * sc;
    }
    __syncthreads();
    GATHER_FEAT(featS)
    f32x4 acc1[2][4];
    layer1(featS, w1b, ln, qq, w, acc1);
#pragma unroll
    for (int rf = 0; rf < 2; ++rf)
#pragma unroll
        for (int nf = 0; nf < 4; ++nf) {
            int col = nf * 16 + ln;
            float sc = sc1L[col], sh = sh1L[col];
            int row0 = w * 32 + rf * 16 + qq * 4;
#pragma unroll
            for (int j = 0; j < 4; ++j)
                h1S[(row0 + j) * 68 + col] = f2b(gelu_t(acc1[rf][nf][j] * sc + sh));
        }
    // L2 (own rows only -> no barrier)
    short8 hA[2][2];
#pragma unroll
    for (int rf = 0; rf < 2; ++rf)
#pragma unroll
        for (int kf = 0; kf < 2; ++kf)
            hA[rf][kf] = ld8(h1S + (w * 32 + rf * 16 + ln) * 68 + kf * 32 + qq * 8);
    f32x4 acc2[2][8];
#pragma unroll
    for (int rf = 0; rf < 2; ++rf)
#pragma unroll
        for (int nf = 0; nf < 8; ++nf) acc2[rf][nf] = zero4();
#pragma unroll
    for (int kf = 0; kf < 2; ++kf)
#pragma unroll
        for (int nf = 0; nf < 8; ++nf) {
            short8 bw = *(const short8*)(w2b + (nf * 16 + ln) * 64 + kf * 32 + qq * 8);
            acc2[0][nf] = mfma(hA[0][kf], bw, acc2[0][nf]);
            acc2[1][nf] = mfma(hA[1][kf], bw, acc2[1][nf]);
        }
#pragma unroll
    for (int nf = 0; nf < 8; ++nf) {
        float s = 0.f, q = 0.f;
#pragma unroll
        for (int rf = 0; rf < 2; ++rf)
#pragma unroll
            for (int j = 0; j < 4; ++j) { float v = acc2[rf][nf][j]; s += v; q += v * v; }
        s += __shfl_xor(s, 16); s += __shfl_xor(s, 32);
        q += __shfl_xor(q, 16); q += __shfl_xor(q, 32);
        if (lane < 16) { redS[w * 128 + nf * 16 + lane] = s; redQ[w * 128 + nf * 16 + lane] = q; }
    }
    __syncthreads();
    if (t < 128) {
        float s = redS[t] + redS[128 + t] + redS[256 + t] + redS[384 + t];
        float q = redQ[t] + redQ[128 + t] + redQ[256 + t] + redQ[384 + t];
        float* st = stats2 + (blockIdx.x & 7) * 256;
        atomicAdd(&st[t], s);
        atomicAdd(&st[128 + t], q);
    }
}

// ---------------- layer3: recompute h1,h2; einsum3 + max (2 barriers total) ----------------
__global__ __launch_bounds__(256, 3) void k_l3(const int* __restrict__ gidx,
                                               const float* __restrict__ src_xyz,
                                               const float* __restrict__ xyz,
                                               const short* __restrict__ src_xb,
                                               const short* __restrict__ w1b,
                                               const short* __restrict__ w2b,
                                               const short* __restrict__ w3b,
                                               const float* __restrict__ g1,
                                               const float* __restrict__ b1,
                                               const float* __restrict__ g2,
                                               const float* __restrict__ b2,
                                               const float* __restrict__ stats1,
                                               const float* __restrict__ stats2,
                                               float* __restrict__ out) {
    __shared__ short ubuf[128 * 136];  // feat (stride 68) -> h2 (stride 136)
    __shared__ short h1S[128 * 68];
    __shared__ int sidx[128];
    __shared__ float sc1L[64], sh1L[64], sc2L[128], sh2L[128];
    int t = threadIdx.x, lane = t & 63, w = t >> 6, ln = lane & 15, qq = lane >> 4;
    int g0 = blockIdx.x * 4, b = g0 >> 10;
    if (t < 128) sidx[t] = gidx[(size_t)(g0 + (t >> 5)) * KNN + (t & 31)];
    if (t < 16) { short4v z = {0, 0, 0, 0}; *(short4v*)(ubuf + 128 * 68 + t * 4) = z; }
    if (t < 64) {
        float s = 0.f, sq = 0.f;
#pragma unroll
        for (int r = 0; r < 8; ++r) { s += stats1[r * 128 + t]; sq += stats1[r * 128 + 64 + t]; }
        float mu = s * (1.f / S1f);
        float var = sq * (1.f / S1f) - mu * mu;
        float rs = rsqrtf(var + EPSV);
        float sc = g1[t] * rs;
        sc1L[t] = sc;
        sh1L[t] = b1[t] - mu * sc;
    }
    if (t < 128) {
        float s = 0.f, sq = 0.f;
#pragma unroll
        for (int r = 0; r < 8; ++r) { s += stats2[r * 256 + t]; sq += stats2[r * 256 + 128 + t]; }
        float mu = s * (1.f / S1f);
        float var = sq * (1.f / S1f) - mu * mu;
        float rs = rsqrtf(var + EPSV);
        float sc = g2[t] * rs;
        sc2L[t] = sc;
        sh2L[t] = b2[t] - mu * sc;
    }
    __syncthreads();  // barrier 1: sidx/pad/scsh visible
    GATHER_FEAT(ubuf)
    f32x4 acc1[2][4];
    layer1(ubuf, w1b, ln, qq, w, acc1);
#pragma unroll
    for (int rf = 0; rf < 2; ++rf)
#pragma unroll
        for (int nf = 0; nf < 4; ++nf) {
            int col = nf * 16 + ln;
            float sc = sc1L[col], sh = sh1L[col];
            int row0 = w * 32 + rf * 16 + qq * 4;
#pragma unroll
            for (int j = 0; j < 4; ++j)
                h1S[(row0 + j) * 68 + col] = f2b(gelu_t(acc1[rf][nf][j] * sc + sh));
        }
    // L2 (own h1 rows)
    short8 hA[2][2];
#pragma unroll
    for (int rf = 0; rf < 2; ++rf)
#pragma unroll
        for (int kf = 0; kf < 2; ++kf)
            hA[rf][kf] = ld8(h1S + (w * 32 + rf * 16 + ln) * 68 + kf * 32 + qq * 8);
    f32x4 acc2[2][8];
#pragma unroll
    for (int rf = 0; rf < 2; ++rf)
#pragma unroll
        for (int nf = 0; nf < 8; ++nf) acc2[rf][nf] = zero4();
#pragma unroll
    for (int kf = 0; kf < 2; ++kf)
#pragma unroll
        for (int nf = 0; nf < 8; ++nf) {
            short8 bw = *(const short8*)(w2b + (nf * 16 + ln) * 64 + kf * 32 + qq * 8);
            acc2[0][nf] = mfma(hA[0][kf], bw, acc2[0][nf]);
            acc2[1][nf] = mfma(hA[1][kf], bw, acc2[1][nf]);
        }
    __syncthreads();  // barrier 2: all feat reads done before ubuf reused as h2
#pragma unroll
    for (int rf = 0; rf < 2; ++rf)
#pragma unroll
        for (int nf = 0; nf < 8; ++nf) {
            int col = nf * 16 + ln;
            float sc = sc2L[col], sh = sh2L[col];
            int row0 = w * 32 + rf * 16 + qq * 4;
#pragma unroll
            for (int j = 0; j < 4; ++j)
                ubuf[(row0 + j) * 136 + col] = f2b(gelu_t(acc2[rf][nf][j] * sc + sh));
        }
    // L3: h2 frags once (own rows); w3 frags from global (L2-resident)
    short8 h2f[2][4];
#pragma unroll
    for (int rf = 0; rf < 2; ++rf)
#pragma unroll
        for (int kf = 0; kf < 4; ++kf)
            h2f[rf][kf] = ld8(ubuf + (w * 32 + rf * 16 + ln) * 136 + kf * 32 + qq * 8);
    int g = g0 + w;
#pragma unroll
    for (int nc = 0; nc < 4; ++nc) {
        f32x4 acc3[2][4];
#pragma unroll
        for (int rf = 0; rf < 2; ++rf)
#pragma unroll
            for (int nf = 0; nf < 4; ++nf) acc3[rf][nf] = zero4();
#pragma unroll
        for (int kf = 0; kf < 4; ++kf)
#pragma unroll
            for (int nf = 0; nf < 4; ++nf) {
                short8 bw = *(const short8*)(w3b + (size_t)(nc * 64 + nf * 16 + ln) * 128 + kf * 32 + qq * 8);
                acc3[0][nf] = mfma(h2f[0][kf], bw, acc3[0][nf]);
                acc3[1][nf] = mfma(h2f[1][kf], bw, acc3[1][nf]);
            }
#pragma unroll
        for (int nf = 0; nf < 4; ++nf) {
            float m = fmaxf(fmaxf(fmaxf(acc3[0][nf][0], acc3[0][nf][1]), fmaxf(acc3[0][nf][2], acc3[0][nf][3])),
                            fmaxf(fmaxf(acc3[1][nf][0], acc3[1][nf][1]), fmaxf(acc3[1][nf][2], acc3[1][nf][3])));
            m = fmaxf(m, __shfl_xor(m, 16));
            m = fmaxf(m, __shfl_xor(m, 32));
            if (lane < 16) out[(size_t)g * 256 + nc * 64 + nf * 16 + lane] = m;
        }
    }
}

// ---------------- stats3 + final BN/GELU ----------------
__global__ __launch_bounds__(256) void k_stats3(const float* __restrict__ out,
                                                float* __restrict__ stats3) {
    int t = threadIdx.x;
    float s = 0.f, q = 0.f;
    const float* p = out + (size_t)blockIdx.x * 128 * 256 + t;
    for (int r = 0; r < 128; ++r) { float v = p[r * 256]; s += v; q += v * v; }
    atomicAdd(&stats3[t], s);
    atomicAdd(&stats3[256 + t], q);
}

__global__ __launch_bounds__(256) void k_bn3(float* __restrict__ out,
                                             const float* __restrict__ stats3,
                                             const float* __restrict__ gl,
                                             const float* __restrict__ bl) {
    int i = blockIdx.x * 256 + threadIdx.x;
    int o = i & 255;
    float mu = stats3[o] * (1.f / S3f);
    float var = stats3[256 + o] * (1.f / S3f) - mu * mu;
    float rs = rsqrtf(var + EPSV);
    float x = out[i];
    out[i] = gelu_e((x - mu) * rs * gl[o] + bl[o]);
}

extern "C" void kernel_launch(void* const* d_in, const int* in_sizes, int n_in,
                              void* d_out, int out_size, void* d_ws, size_t ws_size,
                              hipStream_t stream) {
    const float* src_x   = (const float*)d_in[0];
    const float* src_xyz = (const float*)d_in[1];
    const float* xyz     = (const float*)d_in[2];
    const float* w1      = (const float*)d_in[3];
    const float* g1      = (const float*)d_in[4];
    const float* b1      = (const float*)d_in[5];
    const float* w2      = (const float*)d_in[6];
    const float* g2      = (const float*)d_in[7];
    const float* b2      = (const float*)d_in[8];
    const float* w3      = (const float*)d_in[9];
    const float* gl      = (const float*)d_in[10];
    const float* bl      = (const float*)d_in[11];
    float* out = (float*)d_out;

    int* gidx = (int*)d_ws;                              // 512K ints
    float* statsF = (float*)(gidx + BB * MM * KNN);
    float* stats1 = statsF;          // 8 x (64 sum | 64 sq)
    float* stats2 = statsF + 1024;   // 8 x (128 sum | 128 sq)
    float* stats3 = statsF + 3072;   // 256 sum + 256 sq
    short* wb = (short*)(statsF + 3584);
    short* w1b = wb;                 // [64][96] reordered
    short* w2b = wb + 6144;          // [128][64]
    short* w3b = wb + 14336;         // [256][128]
    short* src_xb = wb + 47104;      // [B][N][64] bf16

    hipMemsetAsync(statsF, 0, 3584 * sizeof(float), stream);
    k_prep<<<2232, 256, 0, stream>>>(src_x, w1, w2, w3, src_xb, w1b, w2b, w3b);
    k_ballquery<<<(BB * MM) / 16, 256, 0, stream>>>(src_xyz, xyz, gidx);
    k_s1<<<(BB * MM) / 4, 256, 0, stream>>>(gidx, src_xyz, xyz, src_xb, w1b, stats1);
    k_s2<<<(BB * MM) / 4, 256, 0, stream>>>(gidx, src_xyz, xyz, src_xb, w1b, w2b, g1, b1,
                                            stats1, stats2);
    k_l3<<<(BB * MM) / 4, 256, 0, stream>>>(gidx, src_xyz, xyz, src_xb, w1b, w2b, w3b,
                                            g1, b1, g2, b2, stats1, stats2, out);
    k_stats3<<<(BB * MM) / 128, 256, 0, stream>>>(out, stats3);
    k_bn3<<<BB * MM, 256, 0, stream>>>(out, stats3, gl, bl);
}